// Round 16
// baseline (49.937 us; speedup 1.0000x reference)
//
#include <hip/hip_runtime.h>

#define DIM   4096
#define BATCH 8192
// One row per 256-thread block (R9-champion structure). Wave q owns quarter
// [1024q, 1024q+1024); lane holds e = 1024q + 256j + 4*lane + i (j,i=0..3).
// Layer L pairs e with e^(1<<L); coeff index c = (4096 - (4096>>L)) + (e >> (L+1)).
// R15 vs R14: the L2..L4 pre-loaded coefficients are PINNED into VGPRs with empty
// asm constraints — R14's preload was silently undone by the register allocator
// (VGPR stayed 32), so the chain-hoist hypothesis was never tested. 24 pinned floats
// + 16 data + overhead ≈ 56-64 VGPR: at/under the 64-VGPR occupancy boundary, so
// 8 waves/SIMD eligibility is preserved (avoids R7/R13's 80-VGPR cliff).
//   L0..L1  : within float4 (i axis)        — register FMAs
//   L2..L7  : lane xor 1,2,4,8,16,32        — quad_perm DPP (1,2), ds_swizzle (4),
//                                             row_ror:8 DPP (8), permlane16_swap (16),
//                                             permlane32_swap (32)   [R9 exact]
//   L8..L9  : register index j distance 1,2 — register FMAs, scalar (s_load) coeffs
//   L10+L11 : cross-wave, FUSED 4-source combine (R3/R6/R9-verified), ONE barrier.
// No pack dispatch; stores nontemporal. Spill tell = WRITE_SIZE > 131072 KB.

#if defined(__has_builtin)
#  if __has_builtin(__builtin_amdgcn_permlane32_swap)
#    define HAVE_PL32 1
#  endif
#  if __has_builtin(__builtin_amdgcn_permlane16_swap)
#    define HAVE_PL16 1
#  endif
#endif
#ifndef HAVE_PL32
#  define HAVE_PL32 0
#endif
#ifndef HAVE_PL16
#  define HAVE_PL16 0
#endif

#define PIN(x) asm volatile("" : "+v"(x))

typedef float f32x4_v __attribute__((ext_vector_type(4)));

__device__ __forceinline__ void store_nt4(float4* p, const float4& v) {
    f32x4_v t; t.x = v.x; t.y = v.y; t.z = v.z; t.w = v.w;
    __builtin_nontemporal_store(t, reinterpret_cast<f32x4_v*>(p));
}

__device__ __forceinline__ void rot2(float& lo, float& hi, float a, float b) {
    float l = lo, h = hi;
    lo = fmaf(a, l,  b * h);   // top =  a*x0 + b*x1
    hi = fmaf(a, h, -b * l);   // bot = -b*x0 + a*x1
}

// Cross-lane xor-M partner fetch (R9 exact primitives).
template<int M>
__device__ __forceinline__ float pxor(float x, bool hi) {
    int xi = __float_as_int(x);
    if constexpr (M == 1)
        return __int_as_float(__builtin_amdgcn_update_dpp(0, xi, 0xB1, 0xF, 0xF, true));
    else if constexpr (M == 2)
        return __int_as_float(__builtin_amdgcn_update_dpp(0, xi, 0x4E, 0xF, 0xF, true));
    else if constexpr (M == 4)
        return __int_as_float(__builtin_amdgcn_ds_swizzle(xi, 0x101F));
    else if constexpr (M == 8)
        return __int_as_float(__builtin_amdgcn_update_dpp(0, xi, 0x128, 0xF, 0xF, true));
    else if constexpr (M == 16) {
#if HAVE_PL16
        unsigned xu = (unsigned)xi;
        auto r = __builtin_amdgcn_permlane16_swap(xu, xu, false, false);
        return __uint_as_float(hi ? r[0] : r[1]);
#else
        return __int_as_float(__builtin_amdgcn_ds_swizzle(xi, 0x401F));
#endif
    } else {
#if HAVE_PL32
        unsigned xu = (unsigned)xi;
        auto r = __builtin_amdgcn_permlane32_swap(xu, xu, false, false);
        return __uint_as_float(hi ? r[0] : r[1]);
#else
        return __shfl_xor(x, 32, 64);
#endif
    }
}

// Layer with PRE-LOADED register coefficients.
template<int M>
__device__ __forceinline__ void shuf_layer_r(float4 (&v)[4], int lane,
                                             const float (&ca)[4], const float (&cb)[4]) {
    const bool hi = (lane & M) != 0;
    #pragma unroll
    for (int j = 0; j < 4; ++j) {
        const float a = ca[j];
        const float sb = hi ? -cb[j] : cb[j];   // top: +b*partner ; bot: -b*partner
        v[j].x = fmaf(a, v[j].x, sb * pxor<M>(v[j].x, hi));
        v[j].y = fmaf(a, v[j].y, sb * pxor<M>(v[j].y, hi));
        v[j].z = fmaf(a, v[j].z, sb * pxor<M>(v[j].z, hi));
        v[j].w = fmaf(a, v[j].w, sb * pxor<M>(v[j].w, hi));
    }
}

// In-chain coeff layer (R9 exact).
template<int M, int JSH, int LSH, bool UNIF>
__device__ __forceinline__ void shuf_layer(float4 (&v)[4], int lane, int base,
                                           const float* __restrict__ af,
                                           const float* __restrict__ bf) {
    const bool hi = (lane & M) != 0;
    #pragma unroll
    for (int j = 0; j < 4; ++j) {
        int c = base + (j << JSH) + (lane >> LSH);
        if constexpr (UNIF) c = __builtin_amdgcn_readfirstlane(c);
        const float a = af[c], b = bf[c];
        const float sb = hi ? -b : b;
        v[j].x = fmaf(a, v[j].x, sb * pxor<M>(v[j].x, hi));
        v[j].y = fmaf(a, v[j].y, sb * pxor<M>(v[j].y, hi));
        v[j].z = fmaf(a, v[j].z, sb * pxor<M>(v[j].z, hi));
        v[j].w = fmaf(a, v[j].w, sb * pxor<M>(v[j].w, hi));
    }
}

__global__ __launch_bounds__(256)
void bfly_kernel(const float* __restrict__ x,
                 const float* __restrict__ af,
                 const float* __restrict__ bf,
                 float* __restrict__ out) {
    const int lane = threadIdx.x & 63;
    const int q    = threadIdx.x >> 6;     // wave index = row quarter
    const size_t row = blockIdx.x;

    const float4* __restrict__ xr = reinterpret_cast<const float4*>(x + row * DIM) + q * 256;
    float4* __restrict__ orow     = reinterpret_cast<float4*>(out + row * DIM) + q * 256;

    __shared__ float4 xch[4][4][64];   // [wave][j][lane] = 16 KB

    // ---- Prologue: x loads + L2..L4 coeff loads issued together, coeffs PINNED ----
    float4 v[4];
    #pragma unroll
    for (int j = 0; j < 4; ++j) v[j] = xr[64 * j + lane];

    float a2[4], b2[4], a3[4], b3[4], a4[4], b4[4];
    #pragma unroll
    for (int j = 0; j < 4; ++j) {   // L2 (M=1):  c = 3072+128q + 32j + (lane>>1)
        const int c = 3072 + 128 * q + (j << 5) + (lane >> 1);
        a2[j] = af[c]; b2[j] = bf[c];
    }
    #pragma unroll
    for (int j = 0; j < 4; ++j) {   // L3 (M=2):  c = 3584+64q + 16j + (lane>>2)
        const int c = 3584 + 64 * q + (j << 4) + (lane >> 2);
        a3[j] = af[c]; b3[j] = bf[c];
    }
    #pragma unroll
    for (int j = 0; j < 4; ++j) {   // L4 (M=4):  c = 3840+32q + 8j + (lane>>3)
        const int c = 3840 + 32 * q + (j << 3) + (lane >> 3);
        a4[j] = af[c]; b4[j] = bf[c];
    }
    #pragma unroll
    for (int j = 0; j < 4; ++j) {   // forbid rematerialization into the chain
        PIN(a2[j]); PIN(b2[j]);
        PIN(a3[j]); PIN(b3[j]);
        PIN(a4[j]); PIN(b4[j]);
    }

    // ---- L0 (bs=1): pairs (x,y),(z,w); c0 = 512q + 128j + 2*lane, c0+1 ----
    #pragma unroll
    for (int j = 0; j < 4; ++j) {
        const int c = 512 * q + 128 * j + 2 * lane;
        float2 aa = *reinterpret_cast<const float2*>(af + c);
        float2 bb = *reinterpret_cast<const float2*>(bf + c);
        rot2(v[j].x, v[j].y, aa.x, bb.x);
        rot2(v[j].z, v[j].w, aa.y, bb.y);
    }

    // ---- L1 (bs=2): pairs (x,z),(y,w); c = 2048 + 256q + 64j + lane ----
    #pragma unroll
    for (int j = 0; j < 4; ++j) {
        const int c = 2048 + 256 * q + 64 * j + lane;
        const float a = af[c], b = bf[c];
        rot2(v[j].x, v[j].z, a, b);
        rot2(v[j].y, v[j].w, a, b);
    }

    // ---- L2..L4: cross-lane layers with pinned register coeffs ----
    shuf_layer_r<1>(v, lane, a2, b2);   // bs=4
    shuf_layer_r<2>(v, lane, a3, b3);   // bs=8
    shuf_layer_r<4>(v, lane, a4, b4);   // bs=16

    // ---- L5..L7: in-chain coeffs (R9 exact) ----
    shuf_layer< 8, 2, 4, false>(v, lane, 3968 + 16 * q, af, bf);  // bs=32
    shuf_layer<16, 1, 5, false>(v, lane, 4032 +  8 * q, af, bf);  // bs=64
    shuf_layer<32, 0, 6, true >(v, lane, 4064 +  4 * q, af, bf);  // bs=128 (uniform)

    // ---- L8 (bs=256): pairs (0,1),(2,3); c = 4080 + 2q + k (uniform -> s_load) ----
    #pragma unroll
    for (int k = 0; k < 2; ++k) {
        const int c = __builtin_amdgcn_readfirstlane(4080 + 2 * q + k);
        const float a = af[c], b = bf[c];
        rot2(v[2*k].x, v[2*k+1].x, a, b);
        rot2(v[2*k].y, v[2*k+1].y, a, b);
        rot2(v[2*k].z, v[2*k+1].z, a, b);
        rot2(v[2*k].w, v[2*k+1].w, a, b);
    }
    // ---- L9 (bs=512): pairs (0,2),(1,3); c = 4088 + q (uniform) ----
    {
        const int c = __builtin_amdgcn_readfirstlane(4088 + q);
        const float a = af[c], b = bf[c];
        #pragma unroll
        for (int j = 0; j < 2; ++j) {
            rot2(v[j].x, v[j+2].x, a, b);
            rot2(v[j].y, v[j+2].y, a, b);
            rot2(v[j].z, v[j+2].z, a, b);
            rot2(v[j].w, v[j+2].w, a, b);
        }
    }

    // ---- L10+L11 fused: one 4-source combine across waves, ONE barrier ----
    {
        const float a0 = af[4092], b0 = bf[4092];
        const float a1 = af[4093], b1 = bf[4093];
        const float A  = af[4094], B  = bf[4094];
        const int h11 = q >> 1, h10 = q & 1;
        const float aO = h11 ? a1 : a0, bO = h11 ? b1 : b0;
        const float aX = h11 ? a0 : a1, bX = h11 ? b0 : b1;
        const float phX = h11 ? -B : B;
        const float w0 = A * aO;
        const float w1 = A * (h10 ? -bO : bO);
        const float w2 = phX * aX;
        const float w3 = phX * (h10 ? -bX : bX);
        const int q1 = q ^ 1, q2 = q ^ 2, q3 = q ^ 3;

        #pragma unroll
        for (int j = 0; j < 4; ++j) xch[q][j][lane] = v[j];
        __syncthreads();
        #pragma unroll
        for (int j = 0; j < 4; ++j) {
            float4 e1 = xch[q1][j][lane];
            float4 e2 = xch[q2][j][lane];
            float4 e3 = xch[q3][j][lane];
            float4 a;
            a.x = fmaf(w3, e3.x, fmaf(w2, e2.x, fmaf(w1, e1.x, w0 * v[j].x)));
            a.y = fmaf(w3, e3.y, fmaf(w2, e2.y, fmaf(w1, e1.y, w0 * v[j].y)));
            a.z = fmaf(w3, e3.z, fmaf(w2, e2.z, fmaf(w1, e1.z, w0 * v[j].z)));
            a.w = fmaf(w3, e3.w, fmaf(w2, e2.w, fmaf(w1, e1.w, w0 * v[j].w)));
            v[j] = a;
        }
    }

    // ---- Store: nontemporal, coalesced 16B/lane ----
    #pragma unroll
    for (int j = 0; j < 4; ++j) store_nt4(&orow[64 * j + lane], v[j]);
}

extern "C" void kernel_launch(void* const* d_in, const int* in_sizes, int n_in,
                              void* d_out, int out_size, void* d_ws, size_t ws_size,
                              hipStream_t stream) {
    const float* x  = (const float*)d_in[0];
    const float* af = (const float*)d_in[1];
    const float* bf = (const float*)d_in[2];
    float* out      = (float*)d_out;
    (void)d_ws; (void)ws_size;

    hipLaunchKernelGGL(bfly_kernel, dim3(BATCH), dim3(256), 0, stream,
                       x, af, bf, out);
}

// Round 17
// 47.928 us; speedup vs baseline: 1.0419x; 1.0419x over previous
//
#include <hip/hip_runtime.h>

#define DIM   4096
#define BATCH 8192
// R9 CHAMPION (47.9 us), reverted bit-for-bit after R10-R15 all lost or nulled.
// One row per 256-thread block. Wave q owns quarter [1024q, 1024q+1024); thread
// lane holds e = 1024q + 256j + 4*lane + i (j,i=0..3).
// Layer L pairs e with e^(1<<L); coeff index c = (4096 - (4096>>L)) + (e >> (L+1)).
//   L0..L1  : within float4 (i axis)        — register FMAs
//   L2..L7  : lane xor 1,2,4,8,16,32        — quad_perm DPP (1,2), ds_swizzle (4),
//                                             row_ror:8 DPP (8), permlane16_swap (16),
//                                             permlane32_swap (32)   [all HW-validated]
//   L8..L9  : register index j distance 1,2 — register FMAs, scalar (s_load) coeffs
//   L10+L11 : cross-wave, FUSED 4-source combine, ONE barrier.
// No pack dispatch; stores nontemporal. Profile: VGPR 32, occ 75%, 0 conflicts,
// 0 spill, 5.35 TB/s logical = 85% of measured copy ceiling — practical roofline
// for a 12-dependent-layer chain with one cross-wave exchange.

#if defined(__has_builtin)
#  if __has_builtin(__builtin_amdgcn_permlane32_swap)
#    define HAVE_PL32 1
#  endif
#  if __has_builtin(__builtin_amdgcn_permlane16_swap)
#    define HAVE_PL16 1
#  endif
#endif
#ifndef HAVE_PL32
#  define HAVE_PL32 0
#endif
#ifndef HAVE_PL16
#  define HAVE_PL16 0
#endif

typedef float f32x4_v __attribute__((ext_vector_type(4)));

__device__ __forceinline__ void store_nt4(float4* p, const float4& v) {
    f32x4_v t; t.x = v.x; t.y = v.y; t.z = v.z; t.w = v.w;
    __builtin_nontemporal_store(t, reinterpret_cast<f32x4_v*>(p));
}

__device__ __forceinline__ void rot2(float& lo, float& hi, float a, float b) {
    float l = lo, h = hi;
    lo = fmaf(a, l,  b * h);   // top =  a*x0 + b*x1
    hi = fmaf(a, h, -b * l);   // bot = -b*x0 + a*x1
}

// Cross-lane xor-M partner fetch on the fastest pipe per M (R6/R8-validated).
template<int M>
__device__ __forceinline__ float pxor(float x, bool hi) {
    int xi = __float_as_int(x);
    if constexpr (M == 1)        // quad_perm [1,0,3,2]
        return __int_as_float(__builtin_amdgcn_update_dpp(0, xi, 0xB1, 0xF, 0xF, true));
    else if constexpr (M == 2)   // quad_perm [2,3,0,1]
        return __int_as_float(__builtin_amdgcn_update_dpp(0, xi, 0x4E, 0xF, 0xF, true));
    else if constexpr (M == 4)   // ds_swizzle BitMode xor 4
        return __int_as_float(__builtin_amdgcn_ds_swizzle(xi, 0x101F));
    else if constexpr (M == 8)   // row_ror:8 within row-of-16 == xor 8
        return __int_as_float(__builtin_amdgcn_update_dpp(0, xi, 0x128, 0xF, 0xF, true));
    else if constexpr (M == 16) {
#if HAVE_PL16
        unsigned xu = (unsigned)xi;
        auto r = __builtin_amdgcn_permlane16_swap(xu, xu, false, false);
        return __uint_as_float(hi ? r[0] : r[1]);
#else
        return __int_as_float(__builtin_amdgcn_ds_swizzle(xi, 0x401F));
#endif
    } else {                     // M == 32
#if HAVE_PL32
        unsigned xu = (unsigned)xi;
        auto r = __builtin_amdgcn_permlane32_swap(xu, xu, false, false);
        return __uint_as_float(hi ? r[0] : r[1]);
#else
        return __shfl_xor(x, 32, 64);
#endif
    }
}

// UNIF: c is wave-uniform -> readfirstlane so the compiler emits s_load (SMEM).
template<int M, int JSH, int LSH, bool UNIF>
__device__ __forceinline__ void shuf_layer(float4 (&v)[4], int lane, int base,
                                           const float* __restrict__ af,
                                           const float* __restrict__ bf) {
    const bool hi = (lane & M) != 0;
    #pragma unroll
    for (int j = 0; j < 4; ++j) {
        int c = base + (j << JSH) + (lane >> LSH);
        if constexpr (UNIF) c = __builtin_amdgcn_readfirstlane(c);
        const float a = af[c], b = bf[c];
        const float sb = hi ? -b : b;   // top: +b*partner ; bot: -b*partner
        v[j].x = fmaf(a, v[j].x, sb * pxor<M>(v[j].x, hi));
        v[j].y = fmaf(a, v[j].y, sb * pxor<M>(v[j].y, hi));
        v[j].z = fmaf(a, v[j].z, sb * pxor<M>(v[j].z, hi));
        v[j].w = fmaf(a, v[j].w, sb * pxor<M>(v[j].w, hi));
    }
}

__global__ __launch_bounds__(256, 7)
void bfly_kernel(const float* __restrict__ x,
                 const float* __restrict__ af,
                 const float* __restrict__ bf,
                 float* __restrict__ out) {
    const int lane = threadIdx.x & 63;
    const int q    = threadIdx.x >> 6;     // wave index = row quarter
    const size_t row = blockIdx.x;

    const float4* __restrict__ xr = reinterpret_cast<const float4*>(x + row * DIM) + q * 256;
    float4* __restrict__ orow     = reinterpret_cast<float4*>(out + row * DIM) + q * 256;

    __shared__ float4 xch[4][4][64];   // [wave][j][lane] = 16 KB

    float4 v[4];
    #pragma unroll
    for (int j = 0; j < 4; ++j) v[j] = xr[64 * j + lane];

    // ---- L0 (bs=1): pairs (x,y),(z,w); c0 = 512q + 128j + 2*lane, c0+1 ----
    #pragma unroll
    for (int j = 0; j < 4; ++j) {
        const int c = 512 * q + 128 * j + 2 * lane;
        float2 aa = *reinterpret_cast<const float2*>(af + c);
        float2 bb = *reinterpret_cast<const float2*>(bf + c);
        rot2(v[j].x, v[j].y, aa.x, bb.x);
        rot2(v[j].z, v[j].w, aa.y, bb.y);
    }

    // ---- L1 (bs=2): pairs (x,z),(y,w); c = 2048 + 256q + 64j + lane ----
    #pragma unroll
    for (int j = 0; j < 4; ++j) {
        const int c = 2048 + 256 * q + 64 * j + lane;
        const float a = af[c], b = bf[c];
        rot2(v[j].x, v[j].z, a, b);
        rot2(v[j].y, v[j].w, a, b);
    }

    // ---- L2..L7: cross-lane layers (DPP / swizzle / permlane) ----
    shuf_layer< 1, 5, 1, false>(v, lane, 3072 + 128 * q, af, bf);  // bs=4
    shuf_layer< 2, 4, 2, false>(v, lane, 3584 +  64 * q, af, bf);  // bs=8
    shuf_layer< 4, 3, 3, false>(v, lane, 3840 +  32 * q, af, bf);  // bs=16
    shuf_layer< 8, 2, 4, false>(v, lane, 3968 +  16 * q, af, bf);  // bs=32
    shuf_layer<16, 1, 5, false>(v, lane, 4032 +   8 * q, af, bf);  // bs=64
    shuf_layer<32, 0, 6, true >(v, lane, 4064 +   4 * q, af, bf);  // bs=128 (uniform)

    // ---- L8 (bs=256): pairs (0,1),(2,3); c = 4080 + 2q + k (uniform -> s_load) ----
    #pragma unroll
    for (int k = 0; k < 2; ++k) {
        const int c = __builtin_amdgcn_readfirstlane(4080 + 2 * q + k);
        const float a = af[c], b = bf[c];
        rot2(v[2*k].x, v[2*k+1].x, a, b);
        rot2(v[2*k].y, v[2*k+1].y, a, b);
        rot2(v[2*k].z, v[2*k+1].z, a, b);
        rot2(v[2*k].w, v[2*k+1].w, a, b);
    }
    // ---- L9 (bs=512): pairs (0,2),(1,3); c = 4088 + q (uniform) ----
    {
        const int c = __builtin_amdgcn_readfirstlane(4088 + q);
        const float a = af[c], b = bf[c];
        #pragma unroll
        for (int j = 0; j < 2; ++j) {
            rot2(v[j].x, v[j+2].x, a, b);
            rot2(v[j].y, v[j+2].y, a, b);
            rot2(v[j].z, v[j+2].z, a, b);
            rot2(v[j].w, v[j+2].w, a, b);
        }
    }

    // ---- L10+L11 fused: one 4-source combine across waves, ONE barrier ----
    {
        const float a0 = af[4092], b0 = bf[4092];   // e11=0  (constant idx -> s_load)
        const float a1 = af[4093], b1 = bf[4093];   // e11=1
        const float A  = af[4094], B  = bf[4094];
        const int h11 = q >> 1, h10 = q & 1;
        const float aO = h11 ? a1 : a0, bO = h11 ? b1 : b0;
        const float aX = h11 ? a0 : a1, bX = h11 ? b0 : b1;
        const float phX = h11 ? -B : B;
        const float w0 = A * aO;
        const float w1 = A * (h10 ? -bO : bO);
        const float w2 = phX * aX;
        const float w3 = phX * (h10 ? -bX : bX);
        const int q1 = q ^ 1, q2 = q ^ 2, q3 = q ^ 3;

        #pragma unroll
        for (int j = 0; j < 4; ++j) xch[q][j][lane] = v[j];
        __syncthreads();
        #pragma unroll
        for (int j = 0; j < 4; ++j) {
            float4 e1 = xch[q1][j][lane];
            float4 e2 = xch[q2][j][lane];
            float4 e3 = xch[q3][j][lane];
            float4 a;
            a.x = fmaf(w3, e3.x, fmaf(w2, e2.x, fmaf(w1, e1.x, w0 * v[j].x)));
            a.y = fmaf(w3, e3.y, fmaf(w2, e2.y, fmaf(w1, e1.y, w0 * v[j].y)));
            a.z = fmaf(w3, e3.z, fmaf(w2, e2.z, fmaf(w1, e1.z, w0 * v[j].z)));
            a.w = fmaf(w3, e3.w, fmaf(w2, e2.w, fmaf(w1, e1.w, w0 * v[j].w)));
            v[j] = a;
        }
    }

    // ---- Store: nontemporal, coalesced 16B/lane ----
    #pragma unroll
    for (int j = 0; j < 4; ++j) store_nt4(&orow[64 * j + lane], v[j]);
}

extern "C" void kernel_launch(void* const* d_in, const int* in_sizes, int n_in,
                              void* d_out, int out_size, void* d_ws, size_t ws_size,
                              hipStream_t stream) {
    const float* x  = (const float*)d_in[0];
    const float* af = (const float*)d_in[1];
    const float* bf = (const float*)d_in[2];
    float* out      = (float*)d_out;
    (void)d_ws; (void)ws_size;

    hipLaunchKernelGGL(bfly_kernel, dim3(BATCH), dim3(256), 0, stream,
                       x, af, bf, out);
}